// Round 7
// baseline (151.141 us; speedup 1.0000x reference)
//
#include <hip/hip_runtime.h>
#include <hip/hip_bf16.h>
#include <math.h>

// Problem constants (fixed by setup_inputs)
#define NB   8          // batch
#define NS   1024       // seq len
#define NDM  512        // d_model
#define NH   8          // heads
#define NDK  64         // d_k
#define NM   8192       // NB*NS

typedef __attribute__((ext_vector_type(8))) short short8;
typedef __attribute__((ext_vector_type(4))) float f32x4;

__device__ __forceinline__ unsigned short f2b(float f) {
    __hip_bfloat16 h = __float2bfloat16(f);
    unsigned short u;
    __builtin_memcpy(&u, &h, 2);
    return u;
}
__device__ __forceinline__ float b2f(unsigned short u) {
    return __uint_as_float(((unsigned)u) << 16);
}
// raw transcendentals (v_exp_f32 is natively 2^x)
__device__ __forceinline__ float exp2_raw(float x) { float r; asm("v_exp_f32 %0, %1" : "=v"(r) : "v"(x)); return r; }
__device__ __forceinline__ float sqrt_raw(float x) { float r; asm("v_sqrt_f32 %0, %1" : "=v"(r) : "v"(x)); return r; }
__device__ __forceinline__ float rcp_raw(float x)  { float r; asm("v_rcp_f32 %0, %1" : "=v"(r) : "v"(x)); return r; }

__device__ __forceinline__ short8 pack8(float4 a, float4 b) {
    short8 r;
    r[0] = (short)f2b(a.x); r[1] = (short)f2b(a.y);
    r[2] = (short)f2b(a.z); r[3] = (short)f2b(a.w);
    r[4] = (short)f2b(b.x); r[5] = (short)f2b(b.y);
    r[6] = (short)f2b(b.z); r[7] = (short)f2b(b.w);
    return r;
}

// C = A @ W^T + bias.  A: NM x 512 (f32 if ACVT else bf16/ushort), W: 512x512 f32.
// OMODE 0: out bf16, head layout [b][h][s][d]
// OMODE 1: out bf16, transposed head layout [b][h][d][s]
// OMODE 2: out f32 row-major [m][n]
template<int OMODE, bool ACVT>
__device__ __forceinline__ void gemm_body(unsigned short* As, unsigned short* Bs,
                                          const void* __restrict__ Ap,
                                          const float* __restrict__ Wf,
                                          const float* __restrict__ bias,
                                          void* __restrict__ outp) {
    const int tid  = threadIdx.x;
    const int lane = tid & 63;
    const int wid  = tid >> 6;
    const int l15  = lane & 15, lhi = lane >> 4;
    const int m0 = (blockIdx.x >> 2) * 128;   // 64 M-tiles
    const int n0 = (blockIdx.x & 3) * 128;    // 4  N-tiles
    const int wr = wid >> 1, wc = wid & 1;

    const float* Af = (const float*)Ap;
    const unsigned short* Ab = (const unsigned short*)Ap;

    f32x4 acc[4][4];
#pragma unroll
    for (int i = 0; i < 4; ++i)
#pragma unroll
        for (int j = 0; j < 4; ++j) acc[i][j] = (f32x4){0.f, 0.f, 0.f, 0.f};

    for (int kk0 = 0; kk0 < NDM; kk0 += 32) {
#pragma unroll
        for (int c = 0; c < 2; ++c) {
            int ci  = tid + 256 * c;           // 0..511
            int row = ci >> 2;
            int kc  = (ci & 3) << 3;
            short8 aval;
            if (ACVT) {
                const float* p = Af + (size_t)(m0 + row) * NDM + kk0 + kc;
                aval = pack8(*(const float4*)p, *(const float4*)(p + 4));
            } else {
                aval = *(const short8*)(Ab + (size_t)(m0 + row) * NDM + kk0 + kc);
            }
            *(short8*)(As + ci * 8) = aval;
            const float* qp = Wf + (size_t)(n0 + row) * NDM + kk0 + kc;
            *(short8*)(Bs + ci * 8) = pack8(*(const float4*)qp, *(const float4*)(qp + 4));
        }
        __syncthreads();
        short8 af[4], bf[4];
#pragma unroll
        for (int mi = 0; mi < 4; ++mi)
            af[mi] = *(const short8*)(As + (wr * 64 + mi * 16 + l15) * 32 + lhi * 8);
#pragma unroll
        for (int ni = 0; ni < 4; ++ni)
            bf[ni] = *(const short8*)(Bs + (wc * 64 + ni * 16 + l15) * 32 + lhi * 8);
#pragma unroll
        for (int mi = 0; mi < 4; ++mi)
#pragma unroll
            for (int ni = 0; ni < 4; ++ni)
                acc[mi][ni] = __builtin_amdgcn_mfma_f32_16x16x32_bf16(af[mi], bf[ni], acc[mi][ni], 0, 0, 0);
        __syncthreads();
    }

#pragma unroll
    for (int mi = 0; mi < 4; ++mi) {
#pragma unroll
        for (int ni = 0; ni < 4; ++ni) {
            int row0 = m0 + wr * 64 + mi * 16 + lhi * 4;
            int col  = n0 + wc * 64 + ni * 16 + l15;
            float bv = bias[col];
            if (OMODE == 0) {
                unsigned short* o = (unsigned short*)outp;
                int h = col >> 6, d = col & 63;
#pragma unroll
                for (int r = 0; r < 4; ++r) {
                    int m = row0 + r;
                    int b = m >> 10, s = m & 1023;
                    o[(size_t)(((b * NH + h) * NS) + s) * NDK + d] = f2b(acc[mi][ni][r] + bv);
                }
            } else if (OMODE == 1) {
                unsigned short* o = (unsigned short*)outp;
                int h = col >> 6, d = col & 63;
                int b = row0 >> 10, s0 = row0 & 1023;
                ushort4 u;
                u.x = f2b(acc[mi][ni][0] + bv);
                u.y = f2b(acc[mi][ni][1] + bv);
                u.z = f2b(acc[mi][ni][2] + bv);
                u.w = f2b(acc[mi][ni][3] + bv);
                *(ushort4*)(o + (size_t)((b * NH + h) * NDK + d) * NS + s0) = u;
            } else {
                float* o = (float*)outp;
#pragma unroll
                for (int r = 0; r < 4; ++r)
                    o[(size_t)(row0 + r) * NDM + col] = acc[mi][ni][r] + bv;
            }
        }
    }
}

// Q, K, V projections fused into one dispatch: grid (256, 3) -> 3 blocks/CU.
__global__ __launch_bounds__(256) void qkv_gemm(const float* __restrict__ q,
                                                const float* __restrict__ k,
                                                const float* __restrict__ v,
                                                const float* __restrict__ Wq,
                                                const float* __restrict__ Wk,
                                                const float* __restrict__ Wv,
                                                const float* __restrict__ bq,
                                                const float* __restrict__ bk,
                                                const float* __restrict__ bv,
                                                unsigned short* __restrict__ Qh,
                                                unsigned short* __restrict__ Kh,
                                                unsigned short* __restrict__ Vt) {
    __shared__ unsigned short As[128 * 32];
    __shared__ unsigned short Bs[128 * 32];
    const int y = blockIdx.y;
    if (y == 0)      gemm_body<0, true>(As, Bs, q, Wq, bq, Qh);
    else if (y == 1) gemm_body<0, true>(As, Bs, k, Wk, bk, Kh);
    else             gemm_body<1, true>(As, Bs, v, Wv, bv, Vt);
}

__global__ __launch_bounds__(256) void wo_gemm(const unsigned short* __restrict__ A,
                                               const float* __restrict__ Wo,
                                               const float* __restrict__ bo,
                                               float* __restrict__ out) {
    __shared__ unsigned short As[128 * 32];
    __shared__ unsigned short Bs[128 * 32];
    gemm_body<2, false>(As, Bs, A, Wo, bo, out);
}

// Fused causal attention with distance decay.
// bf16 LDS tile [16 rows][1024 cols], chunk-swizzled: chunk (c>>3) of row r at (c>>3)^r.
// Scores PRE-SCALED by 0.125*log2(e): softmax math in exp2 domain, no max subtraction.
// Block = q-tile PAIR (p, 63-p) -> uniform work; flat id keeps bh in low 6 bits ->
// head bh pinned to XCD bh%8 (K/V L2-resident).
// 512 threads (8 waves), 4 blocks/CU on 32.1KB LDS -> 32 waves/CU occupancy cap.
// Per wave: phase1 = 16-col strips (stride 128); phase2 = 2 rows; phase3 = half
// the j-range per d0-quarter with LDS partial-reduce (overlaid on prob tile).
__global__ __launch_bounds__(512, 8) void attn_kernel(const unsigned short* __restrict__ Qh,
                                                      const unsigned short* __restrict__ Kh,
                                                      const unsigned short* __restrict__ Vt,
                                                      const float* __restrict__ gammas,
                                                      unsigned short* __restrict__ concat) {
    __shared__ unsigned short pb[16 * 1024];   // 32 KB bf16 tile (scores -> probs in place)
    __shared__ float l2s[16];                  // per-row second-softmax denominators
    const int bh   = blockIdx.x & 63;
    const int pair = blockIdx.x >> 6;          // 0..31
    const int tid = threadIdx.x, lane = tid & 63, wid = tid >> 6;
    const int l15 = lane & 15, lhi = lane >> 4;
    const float SC = 0.125f * 1.44269504f;     // score scale * log2(e)

    const unsigned short* Kb = Kh + (size_t)bh * NS * NDK;
    const unsigned short* Vb = Vt + (size_t)bh * NDK * NS;
    const float g  = gammas[bh & (NH - 1)];
    const float g2 = -log1pf(__expf(g)) * 1.44269504f;   // -softplus * log2(e)
    const int cb = lane * 16;                  // phase-2: lane owns 16 consecutive cols
    const int bq_ = bh >> 3, hq = bh & 7;

    for (int hs = 0; hs < 2; ++hs) {
        const int qt = hs ? (63 - pair) : pair;
        const int r0 = qt * 16;
        const int C  = ((r0 + 16 + 63) >> 6) << 6;   // cols computed (<=1024)

        // ---- Phase 1: swapped QK^T: D[k-local][q-local] = mfma(K_frag, Q_frag) ----
        const unsigned short* Qb = Qh + (size_t)(bh * NS + r0) * NDK;
        short8 qf0 = *(const short8*)(Qb + l15 * NDK + lhi * 8);
        short8 qf1 = *(const short8*)(Qb + l15 * NDK + lhi * 8 + 32);
        for (int j0 = wid * 16; j0 < C; j0 += 128) {
            const unsigned short* kp = Kb + (size_t)(j0 + l15) * NDK + lhi * 8;
            short8 kf0 = *(const short8*)kp;
            short8 kf1 = *(const short8*)(kp + 32);
            f32x4 a = {0.f, 0.f, 0.f, 0.f};
            a = __builtin_amdgcn_mfma_f32_16x16x32_bf16(kf0, qf0, a, 0, 0, 0);
            a = __builtin_amdgcn_mfma_f32_16x16x32_bf16(kf1, qf1, a, 0, 0, 0);
            ushort4 u;
            u.x = f2b(a[0] * SC);
            u.y = f2b(a[1] * SC);
            u.z = f2b(a[2] * SC);
            u.w = f2b(a[3] * SC);
            int ch = ((j0 >> 3) + (lhi >> 1)) ^ l15;
            *(ushort4*)(pb + l15 * 1024 + ch * 8 + (lhi & 1) * 4) = u;
        }
        __syncthreads();

        // ---- Phase 2: softmax1 -> cumsum -> decay -> softmax2 (unnormalized), in place ----
        // wave `wid` owns rows {wid, wid+8}.
#pragma unroll
        for (int t = 0; t < 2; ++t) {
            const int rr = wid + 8 * t;
            const int i  = r0 + rr;
            unsigned short* rowp = pb + rr * 1024;
            short8 raw0 = *(const short8*)(rowp + (((2 * lane)     ^ rr) << 3));
            short8 raw1 = *(const short8*)(rowp + (((2 * lane + 1) ^ rr) << 3));
            float s[16];
#pragma unroll
            for (int u = 0; u < 8; ++u) {
                s[u]     = b2f((unsigned short)raw0[u]);
                s[8 + u] = b2f((unsigned short)raw1[u]);
            }
            // causal mask (also sanitizes garbage beyond C)
#pragma unroll
            for (int u = 0; u < 16; ++u)
                if (cb + u > i) s[u] = -1e30f;
            // softmax1 (no max): exp2 + local inclusive prefix
            float p[16];
            float run = 0.f;
#pragma unroll
            for (int u = 0; u < 16; ++u) { run += exp2_raw(s[u]); p[u] = run; }
            // cross-lane exclusive scan of lane totals
            float inc = run;
#pragma unroll
            for (int off = 1; off < 64; off <<= 1) {
                float y = __shfl_up(inc, off);
                if (lane >= off) inc += y;
            }
            const float l1       = __shfl(inc, 63);
            const float invl1    = rcp_raw(l1);
            const float taillane = l1 - (inc - run);   // l1 - excl
            const float di       = (float)(i - cb);
            // decay + second softmax (unnormalized); masked cols: tail==0 -> te=1 -> w=0
            float l2 = 0.f;
            short8 h0, h1;
#pragma unroll
            for (int u = 0; u < 16; ++u) {
                float tail = fmaxf(taillane - p[u], 0.f);
                float t2   = (tail * invl1) * (di - (float)u);
                float te   = fmaxf(exp2_raw(g2 * sqrt_raw(t2)), 1e-5f);
                float w    = exp2_raw(s[u] * te);
                l2 += w;
                if (u < 8) h0[u] = (short)f2b(w); else h1[u - 8] = (short)f2b(w);
            }
#pragma unroll
            for (int off = 32; off; off >>= 1) l2 += __shfl_xor(l2, off);
            if (lane == 0) l2s[rr] = l2;
            *(short8*)(rowp + (((2 * lane)     ^ rr) << 3)) = h0;
            *(short8*)(rowp + (((2 * lane + 1) ^ rr) << 3)) = h1;
        }
        __syncthreads();

        // ---- Phase 3: out^T = V^T . P^T; wave (d0 = (wid&3)*16, j-half = wid>>2) ----
        const int d0 = (wid & 3) * 16;
        const int jh = wid >> 2;
        f32x4 acc = {0.f, 0.f, 0.f, 0.f};
        for (int j0 = jh * 32; j0 < C; j0 += 64) {
            short8 av = *(const short8*)(Vb + (size_t)(d0 + l15) * NS + j0 + lhi * 8);
            short8 pw = *(const short8*)(pb + l15 * 1024 + (((((j0 >> 3) + lhi)) ^ l15) << 3));
            acc = __builtin_amdgcn_mfma_f32_16x16x32_bf16(av, pw, acc, 0, 0, 0);
        }
        __syncthreads();   // all reads of pb done
        float* scratch = (float*)pb;           // 4 KB overlay for partial sums
        if (jh == 1) *(f32x4*)(scratch + ((wid & 3) * 64 + lane) * 4) = acc;
        __syncthreads();
        if (jh == 0) {
            f32x4 o = *(const f32x4*)(scratch + ((wid & 3) * 64 + lane) * 4);
            float inv2 = rcp_raw(l2s[l15]);
            int d = d0 + lhi * 4;
            int s = r0 + l15;
            ushort4 u;
            u.x = f2b((acc[0] + o[0]) * inv2); u.y = f2b((acc[1] + o[1]) * inv2);
            u.z = f2b((acc[2] + o[2]) * inv2); u.w = f2b((acc[3] + o[3]) * inv2);
            *(ushort4*)(concat + (size_t)(bq_ * NS + s) * NDM + hq * NDK + d) = u;
        }
        __syncthreads();   // pb/l2s reused by the second half
    }
}

extern "C" void kernel_launch(void* const* d_in, const int* in_sizes, int n_in,
                              void* d_out, int out_size, void* d_ws, size_t ws_size,
                              hipStream_t stream) {
    const float* q  = (const float*)d_in[0];
    const float* k  = (const float*)d_in[1];
    const float* v  = (const float*)d_in[2];
    const float* Wq = (const float*)d_in[3];
    const float* bq = (const float*)d_in[4];
    const float* Wk = (const float*)d_in[5];
    const float* bk = (const float*)d_in[6];
    const float* Wv = (const float*)d_in[7];
    const float* bv = (const float*)d_in[8];
    const float* Wo = (const float*)d_in[9];
    const float* bo = (const float*)d_in[10];
    const float* gm = (const float*)d_in[11];

    char* w = (char*)d_ws;
    unsigned short* Qh     = (unsigned short*)(w);
    unsigned short* Kh     = (unsigned short*)(w + (size_t)8388608);
    unsigned short* Vt     = (unsigned short*)(w + (size_t)16777216);
    unsigned short* concat = (unsigned short*)(w + (size_t)25165824);

    qkv_gemm<<<dim3(256, 3), dim3(256), 0, stream>>>(q, k, v, Wq, Wk, Wv, bq, bk, bv, Qh, Kh, Vt);
    attn_kernel<<<dim3(2048), dim3(512), 0, stream>>>(Qh, Kh, Vt, gm, concat);
    wo_gemm<<<dim3(256), dim3(256), 0, stream>>>(concat, Wo, bo, (float*)d_out);
}

// Round 8
// 138.956 us; speedup vs baseline: 1.0877x; 1.0877x over previous
//
#include <hip/hip_runtime.h>
#include <hip/hip_bf16.h>
#include <math.h>

// Problem constants (fixed by setup_inputs)
#define NB   8          // batch
#define NS   1024       // seq len
#define NDM  512        // d_model
#define NH   8          // heads
#define NDK  64         // d_k
#define NM   8192       // NB*NS

typedef __attribute__((ext_vector_type(8))) short short8;
typedef __attribute__((ext_vector_type(4))) float f32x4;

__device__ __forceinline__ unsigned short f2b(float f) {
    __hip_bfloat16 h = __float2bfloat16(f);
    unsigned short u;
    __builtin_memcpy(&u, &h, 2);
    return u;
}
__device__ __forceinline__ float b2f(unsigned short u) {
    return __uint_as_float(((unsigned)u) << 16);
}
// raw transcendentals (v_exp_f32 is natively 2^x)
__device__ __forceinline__ float exp2_raw(float x) { float r; asm("v_exp_f32 %0, %1" : "=v"(r) : "v"(x)); return r; }
__device__ __forceinline__ float sqrt_raw(float x) { float r; asm("v_sqrt_f32 %0, %1" : "=v"(r) : "v"(x)); return r; }
__device__ __forceinline__ float rcp_raw(float x)  { float r; asm("v_rcp_f32 %0, %1" : "=v"(r) : "v"(x)); return r; }

__device__ __forceinline__ short8 pack8(float4 a, float4 b) {
    short8 r;
    r[0] = (short)f2b(a.x); r[1] = (short)f2b(a.y);
    r[2] = (short)f2b(a.z); r[3] = (short)f2b(a.w);
    r[4] = (short)f2b(b.x); r[5] = (short)f2b(b.y);
    r[6] = (short)f2b(b.z); r[7] = (short)f2b(b.w);
    return r;
}

// C = A @ W^T + bias.  A: NM x 512 (f32 if ACVT else bf16/ushort), W: 512x512 f32.
// OMODE 0: out bf16, head layout [b][h][s][d]
// OMODE 1: out bf16, transposed head layout [b][h][d][s]
// OMODE 2: out f32 row-major [m][n]
template<int OMODE, bool ACVT>
__device__ __forceinline__ void gemm_body(unsigned short* As, unsigned short* Bs,
                                          const void* __restrict__ Ap,
                                          const float* __restrict__ Wf,
                                          const float* __restrict__ bias,
                                          void* __restrict__ outp) {
    const int tid  = threadIdx.x;
    const int lane = tid & 63;
    const int wid  = tid >> 6;
    const int l15  = lane & 15, lhi = lane >> 4;
    const int m0 = (blockIdx.x >> 2) * 128;   // 64 M-tiles
    const int n0 = (blockIdx.x & 3) * 128;    // 4  N-tiles
    const int wr = wid >> 1, wc = wid & 1;

    const float* Af = (const float*)Ap;
    const unsigned short* Ab = (const unsigned short*)Ap;

    f32x4 acc[4][4];
#pragma unroll
    for (int i = 0; i < 4; ++i)
#pragma unroll
        for (int j = 0; j < 4; ++j) acc[i][j] = (f32x4){0.f, 0.f, 0.f, 0.f};

    for (int kk0 = 0; kk0 < NDM; kk0 += 32) {
#pragma unroll
        for (int c = 0; c < 2; ++c) {
            int ci  = tid + 256 * c;           // 0..511
            int row = ci >> 2;
            int kc  = (ci & 3) << 3;
            short8 aval;
            if (ACVT) {
                const float* p = Af + (size_t)(m0 + row) * NDM + kk0 + kc;
                aval = pack8(*(const float4*)p, *(const float4*)(p + 4));
            } else {
                aval = *(const short8*)(Ab + (size_t)(m0 + row) * NDM + kk0 + kc);
            }
            *(short8*)(As + ci * 8) = aval;
            const float* qp = Wf + (size_t)(n0 + row) * NDM + kk0 + kc;
            *(short8*)(Bs + ci * 8) = pack8(*(const float4*)qp, *(const float4*)(qp + 4));
        }
        __syncthreads();
        short8 af[4], bf[4];
#pragma unroll
        for (int mi = 0; mi < 4; ++mi)
            af[mi] = *(const short8*)(As + (wr * 64 + mi * 16 + l15) * 32 + lhi * 8);
#pragma unroll
        for (int ni = 0; ni < 4; ++ni)
            bf[ni] = *(const short8*)(Bs + (wc * 64 + ni * 16 + l15) * 32 + lhi * 8);
#pragma unroll
        for (int mi = 0; mi < 4; ++mi)
#pragma unroll
            for (int ni = 0; ni < 4; ++ni)
                acc[mi][ni] = __builtin_amdgcn_mfma_f32_16x16x32_bf16(af[mi], bf[ni], acc[mi][ni], 0, 0, 0);
        __syncthreads();
    }

#pragma unroll
    for (int mi = 0; mi < 4; ++mi) {
#pragma unroll
        for (int ni = 0; ni < 4; ++ni) {
            int row0 = m0 + wr * 64 + mi * 16 + lhi * 4;
            int col  = n0 + wc * 64 + ni * 16 + l15;
            float bv = bias[col];
            if (OMODE == 0) {
                unsigned short* o = (unsigned short*)outp;
                int h = col >> 6, d = col & 63;
#pragma unroll
                for (int r = 0; r < 4; ++r) {
                    int m = row0 + r;
                    int b = m >> 10, s = m & 1023;
                    o[(size_t)(((b * NH + h) * NS) + s) * NDK + d] = f2b(acc[mi][ni][r] + bv);
                }
            } else if (OMODE == 1) {
                unsigned short* o = (unsigned short*)outp;
                int h = col >> 6, d = col & 63;
                int b = row0 >> 10, s0 = row0 & 1023;
                ushort4 u;
                u.x = f2b(acc[mi][ni][0] + bv);
                u.y = f2b(acc[mi][ni][1] + bv);
                u.z = f2b(acc[mi][ni][2] + bv);
                u.w = f2b(acc[mi][ni][3] + bv);
                *(ushort4*)(o + (size_t)((b * NH + h) * NDK + d) * NS + s0) = u;
            } else {
                float* o = (float*)outp;
#pragma unroll
                for (int r = 0; r < 4; ++r)
                    o[(size_t)(row0 + r) * NDM + col] = acc[mi][ni][r] + bv;
            }
        }
    }
}

// Q, K, V projections fused into one dispatch: grid (256, 3) -> 3 blocks/CU.
__global__ __launch_bounds__(256) void qkv_gemm(const float* __restrict__ q,
                                                const float* __restrict__ k,
                                                const float* __restrict__ v,
                                                const float* __restrict__ Wq,
                                                const float* __restrict__ Wk,
                                                const float* __restrict__ Wv,
                                                const float* __restrict__ bq,
                                                const float* __restrict__ bk,
                                                const float* __restrict__ bv,
                                                unsigned short* __restrict__ Qh,
                                                unsigned short* __restrict__ Kh,
                                                unsigned short* __restrict__ Vt) {
    __shared__ unsigned short As[128 * 32];
    __shared__ unsigned short Bs[128 * 32];
    const int y = blockIdx.y;
    if (y == 0)      gemm_body<0, true>(As, Bs, q, Wq, bq, Qh);
    else if (y == 1) gemm_body<0, true>(As, Bs, k, Wk, bk, Kh);
    else             gemm_body<1, true>(As, Bs, v, Wv, bv, Vt);
}

__global__ __launch_bounds__(256) void wo_gemm(const unsigned short* __restrict__ A,
                                               const float* __restrict__ Wo,
                                               const float* __restrict__ bo,
                                               float* __restrict__ out) {
    __shared__ unsigned short As[128 * 32];
    __shared__ unsigned short Bs[128 * 32];
    gemm_body<2, false>(As, Bs, A, Wo, bo, out);
}

// Fused causal attention with distance decay.  (R5 structure restored.)
// bf16 LDS tile [16 rows][1024 cols] = exactly 32768 B -> 5 blocks/CU (20 waves).
// Probs are NORMALIZED in phase 2 (no l2s array -> no LDS overage).
// Scores PRE-SCALED by 0.125*log2(e): softmax math in exp2 domain, no max subtraction.
// Block = q-tile PAIR (p, 63-p) -> uniform work; flat id keeps bh in low 6 bits ->
// head bh pinned to XCD bh%8 (K/V L2-resident; FETCH ~12 MB relies on this).
__global__ __launch_bounds__(256, 5) void attn_kernel(const unsigned short* __restrict__ Qh,
                                                      const unsigned short* __restrict__ Kh,
                                                      const unsigned short* __restrict__ Vt,
                                                      const float* __restrict__ gammas,
                                                      unsigned short* __restrict__ concat) {
    __shared__ unsigned short pb[16 * 1024];   // 32 KB bf16 tile (scores -> probs in place)
    const int bh   = blockIdx.x & 63;
    const int pair = blockIdx.x >> 6;          // 0..31
    const int tid = threadIdx.x, lane = tid & 63, wid = tid >> 6;
    const int l15 = lane & 15, lhi = lane >> 4;
    const float SC = 0.125f * 1.44269504f;     // score scale * log2(e)

    const unsigned short* Kb = Kh + (size_t)bh * NS * NDK;
    const unsigned short* Vb = Vt + (size_t)bh * NDK * NS;
    const float g  = gammas[bh & (NH - 1)];
    const float g2 = -log1pf(__expf(g)) * 1.44269504f;   // -softplus * log2(e)
    const int cb = lane * 16;                  // phase-2: lane owns 16 consecutive cols
    const int bq_ = bh >> 3, hq = bh & 7;

    for (int hs = 0; hs < 2; ++hs) {
        const int qt = hs ? (63 - pair) : pair;
        const int r0 = qt * 16;
        const int C  = ((r0 + 16 + 63) >> 6) << 6;   // cols computed (<=1024)

        // ---- Phase 1: swapped QK^T: D[k-local][q-local] = mfma(K_frag, Q_frag) ----
        const unsigned short* Qb = Qh + (size_t)(bh * NS + r0) * NDK;
        short8 qf0 = *(const short8*)(Qb + l15 * NDK + lhi * 8);
        short8 qf1 = *(const short8*)(Qb + l15 * NDK + lhi * 8 + 32);
        for (int j0 = wid * 16; j0 < C; j0 += 64) {
            const unsigned short* kp = Kb + (size_t)(j0 + l15) * NDK + lhi * 8;
            short8 kf0 = *(const short8*)kp;
            short8 kf1 = *(const short8*)(kp + 32);
            f32x4 a = {0.f, 0.f, 0.f, 0.f};
            a = __builtin_amdgcn_mfma_f32_16x16x32_bf16(kf0, qf0, a, 0, 0, 0);
            a = __builtin_amdgcn_mfma_f32_16x16x32_bf16(kf1, qf1, a, 0, 0, 0);
            ushort4 u;
            u.x = f2b(a[0] * SC);
            u.y = f2b(a[1] * SC);
            u.z = f2b(a[2] * SC);
            u.w = f2b(a[3] * SC);
            int ch = ((j0 >> 3) + (lhi >> 1)) ^ l15;
            *(ushort4*)(pb + l15 * 1024 + ch * 8 + (lhi & 1) * 4) = u;
        }
        __syncthreads();

        // ---- Phase 2: softmax1 -> cumsum -> decay -> softmax2 (normalized), in place ----
        // wave `wid` owns rows {wid, wid+4, wid+8, wid+12}.
#pragma unroll
        for (int t = 0; t < 4; ++t) {
            const int rr = wid + 4 * t;
            const int i  = r0 + rr;
            unsigned short* rowp = pb + rr * 1024;
            short8 raw0 = *(const short8*)(rowp + (((2 * lane)     ^ rr) << 3));
            short8 raw1 = *(const short8*)(rowp + (((2 * lane + 1) ^ rr) << 3));
            float s[16];
#pragma unroll
            for (int u = 0; u < 8; ++u) {
                s[u]     = b2f((unsigned short)raw0[u]);
                s[8 + u] = b2f((unsigned short)raw1[u]);
            }
            // causal mask (also sanitizes garbage beyond C)
#pragma unroll
            for (int u = 0; u < 16; ++u)
                if (cb + u > i) s[u] = -1e30f;
            // softmax1 (no max): exp2 + local inclusive prefix
            float p[16];
            float run = 0.f;
#pragma unroll
            for (int u = 0; u < 16; ++u) { run += exp2_raw(s[u]); p[u] = run; }
            // cross-lane exclusive scan of lane totals
            float inc = run;
#pragma unroll
            for (int off = 1; off < 64; off <<= 1) {
                float y = __shfl_up(inc, off);
                if (lane >= off) inc += y;
            }
            const float l1       = __shfl(inc, 63);
            const float invl1    = rcp_raw(l1);
            const float taillane = l1 - (inc - run);   // l1 - excl
            const float di       = (float)(i - cb);
            // decay + second softmax; masked cols: tail==0 -> te=1 -> w=0
            float l2 = 0.f;
#pragma unroll
            for (int u = 0; u < 16; ++u) {
                float tail = fmaxf(taillane - p[u], 0.f);
                float t2   = (tail * invl1) * (di - (float)u);
                float te   = fmaxf(exp2_raw(g2 * sqrt_raw(t2)), 1e-5f);
                float w    = exp2_raw(s[u] * te);
                s[u] = w;
                l2 += w;
            }
#pragma unroll
            for (int off = 32; off; off >>= 1) l2 += __shfl_xor(l2, off);
            const float inv2 = rcp_raw(l2);
            short8 h0, h1;
#pragma unroll
            for (int u = 0; u < 8; ++u) {
                h0[u] = (short)f2b(s[u] * inv2);
                h1[u] = (short)f2b(s[8 + u] * inv2);
            }
            *(short8*)(rowp + (((2 * lane)     ^ rr) << 3)) = h0;
            *(short8*)(rowp + (((2 * lane + 1) ^ rr) << 3)) = h1;
        }
        __syncthreads();

        // ---- Phase 3: out^T = V^T . P^T via mfma(v_frag, p_frag) ----
        const int d0 = wid * 16;
        f32x4 acc = {0.f, 0.f, 0.f, 0.f};
        for (int j0 = 0; j0 < C; j0 += 32) {
            short8 av = *(const short8*)(Vb + (size_t)(d0 + l15) * NS + j0 + lhi * 8);
            short8 pw = *(const short8*)(pb + l15 * 1024 + (((((j0 >> 3) + lhi)) ^ l15) << 3));
            acc = __builtin_amdgcn_mfma_f32_16x16x32_bf16(av, pw, acc, 0, 0, 0);
        }
        {
            int d = d0 + lhi * 4;
            int s = r0 + l15;
            ushort4 u;
            u.x = f2b(acc[0]); u.y = f2b(acc[1]);
            u.z = f2b(acc[2]); u.w = f2b(acc[3]);
            *(ushort4*)(concat + (size_t)(bq_ * NS + s) * NDM + hq * NDK + d) = u;
        }
        __syncthreads();   // pb reused by the second half
    }
}

extern "C" void kernel_launch(void* const* d_in, const int* in_sizes, int n_in,
                              void* d_out, int out_size, void* d_ws, size_t ws_size,
                              hipStream_t stream) {
    const float* q  = (const float*)d_in[0];
    const float* k  = (const float*)d_in[1];
    const float* v  = (const float*)d_in[2];
    const float* Wq = (const float*)d_in[3];
    const float* bq = (const float*)d_in[4];
    const float* Wk = (const float*)d_in[5];
    const float* bk = (const float*)d_in[6];
    const float* Wv = (const float*)d_in[7];
    const float* bv = (const float*)d_in[8];
    const float* Wo = (const float*)d_in[9];
    const float* bo = (const float*)d_in[10];
    const float* gm = (const float*)d_in[11];

    char* w = (char*)d_ws;
    unsigned short* Qh     = (unsigned short*)(w);
    unsigned short* Kh     = (unsigned short*)(w + (size_t)8388608);
    unsigned short* Vt     = (unsigned short*)(w + (size_t)16777216);
    unsigned short* concat = (unsigned short*)(w + (size_t)25165824);

    qkv_gemm<<<dim3(256, 3), dim3(256), 0, stream>>>(q, k, v, Wq, Wk, Wv, bq, bk, bv, Qh, Kh, Vt);
    attn_kernel<<<dim3(2048), dim3(256), 0, stream>>>(Qh, Kh, Vt, gm, concat);
    wo_gemm<<<dim3(256), dim3(256), 0, stream>>>(concat, Wo, bo, (float*)d_out);
}

// Round 9
// 135.692 us; speedup vs baseline: 1.1139x; 1.0241x over previous
//
#include <hip/hip_runtime.h>
#include <hip/hip_bf16.h>
#include <math.h>

// Problem constants (fixed by setup_inputs)
#define NB   8          // batch
#define NS   1024       // seq len
#define NDM  512        // d_model
#define NH   8          // heads
#define NDK  64         // d_k
#define NM   8192       // NB*NS

typedef __attribute__((ext_vector_type(8))) short short8;
typedef __attribute__((ext_vector_type(4))) float f32x4;

__device__ __forceinline__ unsigned short f2b(float f) {
    __hip_bfloat16 h = __float2bfloat16(f);
    unsigned short u;
    __builtin_memcpy(&u, &h, 2);
    return u;
}
__device__ __forceinline__ float b2f(unsigned short u) {
    return __uint_as_float(((unsigned)u) << 16);
}
// raw transcendentals (v_exp_f32 is natively 2^x)
__device__ __forceinline__ float exp2_raw(float x) { float r; asm("v_exp_f32 %0, %1" : "=v"(r) : "v"(x)); return r; }
__device__ __forceinline__ float sqrt_raw(float x) { float r; asm("v_sqrt_f32 %0, %1" : "=v"(r) : "v"(x)); return r; }
__device__ __forceinline__ float rcp_raw(float x)  { float r; asm("v_rcp_f32 %0, %1" : "=v"(r) : "v"(x)); return r; }

// DPP helper: returns src moved by CTRL; lanes where the move is invalid/masked get 0.
// (old=0, bound_ctrl=true). Used as x += dpp_mov0<...>(x) -> folds to v_add_f32_dpp.
template<int CTRL, int RM>
__device__ __forceinline__ float dpp_mov0(float x) {
    int m = __builtin_amdgcn_update_dpp(0, __float_as_int(x), CTRL, RM, 0xf, true);
    return __int_as_float(m);
}
// wave64 inclusive scan (GCN idiom): row-local scan + hierarchical row-total adds
__device__ __forceinline__ float wave_incl_scan(float x) {
    x += dpp_mov0<0x111, 0xf>(x);   // row_shr:1
    x += dpp_mov0<0x112, 0xf>(x);   // row_shr:2
    x += dpp_mov0<0x114, 0xf>(x);   // row_shr:4
    x += dpp_mov0<0x118, 0xf>(x);   // row_shr:8
    x += dpp_mov0<0x142, 0xa>(x);   // row_bcast:15 -> rows 1,3
    x += dpp_mov0<0x143, 0xc>(x);   // row_bcast:31 -> rows 2,3
    return x;
}
__device__ __forceinline__ float lane63(float x) {
    return __int_as_float(__builtin_amdgcn_readlane(__float_as_int(x), 63));
}

__device__ __forceinline__ short8 pack8(float4 a, float4 b) {
    short8 r;
    r[0] = (short)f2b(a.x); r[1] = (short)f2b(a.y);
    r[2] = (short)f2b(a.z); r[3] = (short)f2b(a.w);
    r[4] = (short)f2b(b.x); r[5] = (short)f2b(b.y);
    r[6] = (short)f2b(b.z); r[7] = (short)f2b(b.w);
    return r;
}

// C = A @ W^T + bias.  A: NM x 512 (f32 if ACVT else bf16/ushort), W: 512x512 f32.
// OMODE 0: out bf16, head layout [b][h][s][d]
// OMODE 1: out bf16, transposed head layout [b][h][d][s]
// OMODE 2: out f32 row-major [m][n]
template<int OMODE, bool ACVT>
__device__ __forceinline__ void gemm_body(unsigned short* As, unsigned short* Bs,
                                          const void* __restrict__ Ap,
                                          const float* __restrict__ Wf,
                                          const float* __restrict__ bias,
                                          void* __restrict__ outp) {
    const int tid  = threadIdx.x;
    const int lane = tid & 63;
    const int wid  = tid >> 6;
    const int l15  = lane & 15, lhi = lane >> 4;
    const int m0 = (blockIdx.x >> 2) * 128;   // 64 M-tiles
    const int n0 = (blockIdx.x & 3) * 128;    // 4  N-tiles
    const int wr = wid >> 1, wc = wid & 1;

    const float* Af = (const float*)Ap;
    const unsigned short* Ab = (const unsigned short*)Ap;

    f32x4 acc[4][4];
#pragma unroll
    for (int i = 0; i < 4; ++i)
#pragma unroll
        for (int j = 0; j < 4; ++j) acc[i][j] = (f32x4){0.f, 0.f, 0.f, 0.f};

    for (int kk0 = 0; kk0 < NDM; kk0 += 32) {
#pragma unroll
        for (int c = 0; c < 2; ++c) {
            int ci  = tid + 256 * c;           // 0..511
            int row = ci >> 2;
            int kc  = (ci & 3) << 3;
            short8 aval;
            if (ACVT) {
                const float* p = Af + (size_t)(m0 + row) * NDM + kk0 + kc;
                aval = pack8(*(const float4*)p, *(const float4*)(p + 4));
            } else {
                aval = *(const short8*)(Ab + (size_t)(m0 + row) * NDM + kk0 + kc);
            }
            *(short8*)(As + ci * 8) = aval;
            const float* qp = Wf + (size_t)(n0 + row) * NDM + kk0 + kc;
            *(short8*)(Bs + ci * 8) = pack8(*(const float4*)qp, *(const float4*)(qp + 4));
        }
        __syncthreads();
        short8 af[4], bf[4];
#pragma unroll
        for (int mi = 0; mi < 4; ++mi)
            af[mi] = *(const short8*)(As + (wr * 64 + mi * 16 + l15) * 32 + lhi * 8);
#pragma unroll
        for (int ni = 0; ni < 4; ++ni)
            bf[ni] = *(const short8*)(Bs + (wc * 64 + ni * 16 + l15) * 32 + lhi * 8);
#pragma unroll
        for (int mi = 0; mi < 4; ++mi)
#pragma unroll
            for (int ni = 0; ni < 4; ++ni)
                acc[mi][ni] = __builtin_amdgcn_mfma_f32_16x16x32_bf16(af[mi], bf[ni], acc[mi][ni], 0, 0, 0);
        __syncthreads();
    }

#pragma unroll
    for (int mi = 0; mi < 4; ++mi) {
#pragma unroll
        for (int ni = 0; ni < 4; ++ni) {
            int row0 = m0 + wr * 64 + mi * 16 + lhi * 4;
            int col  = n0 + wc * 64 + ni * 16 + l15;
            float bv = bias[col];
            if (OMODE == 0) {
                unsigned short* o = (unsigned short*)outp;
                int h = col >> 6, d = col & 63;
#pragma unroll
                for (int r = 0; r < 4; ++r) {
                    int m = row0 + r;
                    int b = m >> 10, s = m & 1023;
                    o[(size_t)(((b * NH + h) * NS) + s) * NDK + d] = f2b(acc[mi][ni][r] + bv);
                }
            } else if (OMODE == 1) {
                unsigned short* o = (unsigned short*)outp;
                int h = col >> 6, d = col & 63;
                int b = row0 >> 10, s0 = row0 & 1023;
                ushort4 u;
                u.x = f2b(acc[mi][ni][0] + bv);
                u.y = f2b(acc[mi][ni][1] + bv);
                u.z = f2b(acc[mi][ni][2] + bv);
                u.w = f2b(acc[mi][ni][3] + bv);
                *(ushort4*)(o + (size_t)((b * NH + h) * NDK + d) * NS + s0) = u;
            } else {
                float* o = (float*)outp;
#pragma unroll
                for (int r = 0; r < 4; ++r)
                    o[(size_t)(row0 + r) * NDM + col] = acc[mi][ni][r] + bv;
            }
        }
    }
}

// Q, K, V projections fused into one dispatch: grid (256, 3) -> 3 blocks/CU.
__global__ __launch_bounds__(256) void qkv_gemm(const float* __restrict__ q,
                                                const float* __restrict__ k,
                                                const float* __restrict__ v,
                                                const float* __restrict__ Wq,
                                                const float* __restrict__ Wk,
                                                const float* __restrict__ Wv,
                                                const float* __restrict__ bq,
                                                const float* __restrict__ bk,
                                                const float* __restrict__ bv,
                                                unsigned short* __restrict__ Qh,
                                                unsigned short* __restrict__ Kh,
                                                unsigned short* __restrict__ Vt) {
    __shared__ unsigned short As[128 * 32];
    __shared__ unsigned short Bs[128 * 32];
    const int y = blockIdx.y;
    if (y == 0)      gemm_body<0, true>(As, Bs, q, Wq, bq, Qh);
    else if (y == 1) gemm_body<0, true>(As, Bs, k, Wk, bk, Kh);
    else             gemm_body<1, true>(As, Bs, v, Wv, bv, Vt);
}

__global__ __launch_bounds__(256) void wo_gemm(const unsigned short* __restrict__ A,
                                               const float* __restrict__ Wo,
                                               const float* __restrict__ bo,
                                               float* __restrict__ out) {
    __shared__ unsigned short As[128 * 32];
    __shared__ unsigned short Bs[128 * 32];
    gemm_body<2, false>(As, Bs, A, Wo, bo, out);
}

// Fused causal attention with distance decay.
// bf16 LDS tile [16 rows][1024 cols] = 32768 B.  Probs normalized in phase 2.
// Cross-lane scan/reduce via DPP (row_shr + row_bcast) at VALU rate — no
// ds_bpermute latency on the phase-2 critical path.
// Block = q-tile PAIR (p, 63-p) -> uniform work; bh in low 6 bits of flat id
// pins head bh to XCD bh%8 (K/V L2-resident; FETCH ~12 MB relies on this).
__global__ __launch_bounds__(256, 4) void attn_kernel(const unsigned short* __restrict__ Qh,
                                                      const unsigned short* __restrict__ Kh,
                                                      const unsigned short* __restrict__ Vt,
                                                      const float* __restrict__ gammas,
                                                      unsigned short* __restrict__ concat) {
    __shared__ unsigned short pb[16 * 1024];   // 32 KB bf16 tile (scores -> probs in place)
    const int bh   = blockIdx.x & 63;
    const int pair = blockIdx.x >> 6;          // 0..31
    const int tid = threadIdx.x, lane = tid & 63, wid = tid >> 6;
    const int l15 = lane & 15, lhi = lane >> 4;
    const float SC = 0.125f * 1.44269504f;     // score scale * log2(e)

    const unsigned short* Kb = Kh + (size_t)bh * NS * NDK;
    const unsigned short* Vb = Vt + (size_t)bh * NDK * NS;
    const float g  = gammas[bh & (NH - 1)];
    const float g2 = -log1pf(__expf(g)) * 1.44269504f;   // -softplus * log2(e)
    const int cb = lane * 16;                  // phase-2: lane owns 16 consecutive cols
    const int bq_ = bh >> 3, hq = bh & 7;

    for (int hs = 0; hs < 2; ++hs) {
        const int qt = hs ? (63 - pair) : pair;
        const int r0 = qt * 16;
        const int C  = ((r0 + 16 + 63) >> 6) << 6;   // cols computed (<=1024)

        // ---- Phase 1: swapped QK^T: D[k-local][q-local] = mfma(K_frag, Q_frag) ----
        const unsigned short* Qb = Qh + (size_t)(bh * NS + r0) * NDK;
        short8 qf0 = *(const short8*)(Qb + l15 * NDK + lhi * 8);
        short8 qf1 = *(const short8*)(Qb + l15 * NDK + lhi * 8 + 32);
        for (int j0 = wid * 16; j0 < C; j0 += 64) {
            const unsigned short* kp = Kb + (size_t)(j0 + l15) * NDK + lhi * 8;
            short8 kf0 = *(const short8*)kp;
            short8 kf1 = *(const short8*)(kp + 32);
            f32x4 a = {0.f, 0.f, 0.f, 0.f};
            a = __builtin_amdgcn_mfma_f32_16x16x32_bf16(kf0, qf0, a, 0, 0, 0);
            a = __builtin_amdgcn_mfma_f32_16x16x32_bf16(kf1, qf1, a, 0, 0, 0);
            ushort4 u;
            u.x = f2b(a[0] * SC);
            u.y = f2b(a[1] * SC);
            u.z = f2b(a[2] * SC);
            u.w = f2b(a[3] * SC);
            int ch = ((j0 >> 3) + (lhi >> 1)) ^ l15;
            *(ushort4*)(pb + l15 * 1024 + ch * 8 + (lhi & 1) * 4) = u;
        }
        __syncthreads();

        // ---- Phase 2: softmax1 -> cumsum -> decay -> softmax2 (normalized), in place ----
        // wave `wid` owns rows {wid, wid+4, wid+8, wid+12}.
#pragma unroll
        for (int t = 0; t < 4; ++t) {
            const int rr = wid + 4 * t;
            const int i  = r0 + rr;
            unsigned short* rowp = pb + rr * 1024;
            short8 raw0 = *(const short8*)(rowp + (((2 * lane)     ^ rr) << 3));
            short8 raw1 = *(const short8*)(rowp + (((2 * lane + 1) ^ rr) << 3));
            float s[16];
#pragma unroll
            for (int u = 0; u < 8; ++u) {
                s[u]     = b2f((unsigned short)raw0[u]);
                s[8 + u] = b2f((unsigned short)raw1[u]);
            }
            // causal mask (also sanitizes garbage beyond C)
#pragma unroll
            for (int u = 0; u < 16; ++u)
                if (cb + u > i) s[u] = -1e30f;
            // softmax1 (no max): exp2 + local inclusive prefix
            float p[16];
            float run = 0.f;
#pragma unroll
            for (int u = 0; u < 16; ++u) { run += exp2_raw(s[u]); p[u] = run; }
            // cross-lane inclusive scan of lane totals (DPP, VALU-rate)
            const float inc      = wave_incl_scan(run);
            const float l1       = lane63(inc);
            const float invl1    = rcp_raw(l1);
            const float taillane = l1 - (inc - run);   // l1 - excl
            const float di       = (float)(i - cb);
            // decay + second softmax; masked cols: tail==0 -> te=1 -> w=0
            float l2 = 0.f;
#pragma unroll
            for (int u = 0; u < 16; ++u) {
                float tail = fmaxf(taillane - p[u], 0.f);
                float t2   = (tail * invl1) * (di - (float)u);
                float te   = fmaxf(exp2_raw(g2 * sqrt_raw(t2)), 1e-5f);
                float w    = exp2_raw(s[u] * te);
                s[u] = w;
                l2 += w;
            }
            const float l2t  = lane63(wave_incl_scan(l2));
            const float inv2 = rcp_raw(l2t);
            short8 h0, h1;
#pragma unroll
            for (int u = 0; u < 8; ++u) {
                h0[u] = (short)f2b(s[u] * inv2);
                h1[u] = (short)f2b(s[8 + u] * inv2);
            }
            *(short8*)(rowp + (((2 * lane)     ^ rr) << 3)) = h0;
            *(short8*)(rowp + (((2 * lane + 1) ^ rr) << 3)) = h1;
        }
        __syncthreads();

        // ---- Phase 3: out^T = V^T . P^T via mfma(v_frag, p_frag) ----
        const int d0 = wid * 16;
        f32x4 acc = {0.f, 0.f, 0.f, 0.f};
        for (int j0 = 0; j0 < C; j0 += 32) {
            short8 av = *(const short8*)(Vb + (size_t)(d0 + l15) * NS + j0 + lhi * 8);
            short8 pw = *(const short8*)(pb + l15 * 1024 + (((((j0 >> 3) + lhi)) ^ l15) << 3));
            acc = __builtin_amdgcn_mfma_f32_16x16x32_bf16(av, pw, acc, 0, 0, 0);
        }
        {
            int d = d0 + lhi * 4;
            int s = r0 + l15;
            ushort4 u;
            u.x = f2b(acc[0]); u.y = f2b(acc[1]);
            u.z = f2b(acc[2]); u.w = f2b(acc[3]);
            *(ushort4*)(concat + (size_t)(bq_ * NS + s) * NDM + hq * NDK + d) = u;
        }
        __syncthreads();   // pb reused by the second half
    }
}

extern "C" void kernel_launch(void* const* d_in, const int* in_sizes, int n_in,
                              void* d_out, int out_size, void* d_ws, size_t ws_size,
                              hipStream_t stream) {
    const float* q  = (const float*)d_in[0];
    const float* k  = (const float*)d_in[1];
    const float* v  = (const float*)d_in[2];
    const float* Wq = (const float*)d_in[3];
    const float* bq = (const float*)d_in[4];
    const float* Wk = (const float*)d_in[5];
    const float* bk = (const float*)d_in[6];
    const float* Wv = (const float*)d_in[7];
    const float* bv = (const float*)d_in[8];
    const float* Wo = (const float*)d_in[9];
    const float* bo = (const float*)d_in[10];
    const float* gm = (const float*)d_in[11];

    char* w = (char*)d_ws;
    unsigned short* Qh     = (unsigned short*)(w);
    unsigned short* Kh     = (unsigned short*)(w + (size_t)8388608);
    unsigned short* Vt     = (unsigned short*)(w + (size_t)16777216);
    unsigned short* concat = (unsigned short*)(w + (size_t)25165824);

    qkv_gemm<<<dim3(256, 3), dim3(256), 0, stream>>>(q, k, v, Wq, Wk, Wv, bq, bk, bv, Qh, Kh, Vt);
    attn_kernel<<<dim3(2048), dim3(256), 0, stream>>>(Qh, Kh, Vt, gm, concat);
    wo_gemm<<<dim3(256), dim3(256), 0, stream>>>(concat, Wo, bo, (float*)d_out);
}